// Round 3
// baseline (471.021 us; speedup 1.0000x reference)
//
#include <hip/hip_runtime.h>

#define EPSF 1e-5f
#define DECAYF 0.99f
#define KCODES 2048
#define DIM 256
#define BM 256
#define NKT 8         // 2048 / 256 cols per tile
#define STEPS 192     // NKT * 24 virtual k-steps (K=768 / 32)

typedef _Float16 f16;
typedef f16 f16x8 __attribute__((ext_vector_type(8)));
typedef float f32x4 __attribute__((ext_vector_type(4)));

#define MFMA16(A, B, C) __builtin_amdgcn_mfma_f32_16x16x32_f16(A, B, C, 0, 0, 0)

__device__ __forceinline__ void gload_lds16(const void* g, void* l) {
    __builtin_amdgcn_global_load_lds(
        (const __attribute__((address_space(1))) void*)g,
        (__attribute__((address_space(3))) void*)l, 16, 0, 0);
}

// ---------------------------------------------------------------------------
// split_x: xh = (f16)x, xl = (f16)(x - xh)   [N*D elements, 8 per thread]
// ---------------------------------------------------------------------------
__global__ __launch_bounds__(256) void split_x_kernel(
    const float* __restrict__ x, f16* __restrict__ xh, f16* __restrict__ xl, int n8)
{
    int i = blockIdx.x * 256 + threadIdx.x;
    if (i >= n8) return;
    f32x4 v0 = ((const f32x4*)x)[2 * i];
    f32x4 v1 = ((const f32x4*)x)[2 * i + 1];
    f16x8 h, l;
    #pragma unroll
    for (int t = 0; t < 4; ++t) {
        f16 h0 = (f16)v0[t]; h[t] = h0; l[t] = (f16)(v0[t] - (float)h0);
        f16 h1 = (f16)v1[t]; h[t + 4] = h1; l[t + 4] = (f16)(v1[t] - (float)h1);
    }
    ((f16x8*)xh)[i] = h;
    ((f16x8*)xl)[i] = l;
}

// ---------------------------------------------------------------------------
// prep: embed fp32 = embed_sum / clamp(usage); e2 = ||embed||^2;
//       eh/el = saturated f16 split of embed.
// ---------------------------------------------------------------------------
__global__ __launch_bounds__(256) void prep_embed_kernel(
    const float* __restrict__ embed_sum, const float* __restrict__ usage,
    float* __restrict__ embed, f16* __restrict__ eh, f16* __restrict__ el,
    float* __restrict__ e2)
{
    int k = blockIdx.x;
    int d = threadIdx.x;
    float inv = 1.0f / fmaxf(usage[k], EPSF);
    float e = embed_sum[k * DIM + d] * inv;
    embed[k * DIM + d] = e;
    float ec = fminf(fmaxf(e, -65000.0f), 65000.0f);
    f16 h = (f16)ec;
    f16 l = (f16)(ec - (float)h);
    eh[k * DIM + d] = h;
    el[k * DIM + d] = l;
    float sq = e * e;
    #pragma unroll
    for (int off = 32; off > 0; off >>= 1) sq += __shfl_down(sq, off, 64);
    __shared__ float ws[4];
    if ((threadIdx.x & 63) == 0) ws[threadIdx.x >> 6] = sq;
    __syncthreads();
    if (threadIdx.x == 0) e2[k] = ws[0] + ws[1] + ws[2] + ws[3];
}

// ---------------------------------------------------------------------------
// argmin: pure-f16 GEMM-argmin, virtual K = 768 (xh.eh + xh.el + xl.eh).
// BM=256 rows x BN=256 code-tile, 8 waves (4x2, wave tile 64x128),
// mfma 16x16x32 f16, BK=32, 3 rotating LDS buffers, depth-2 counted-vmcnt
// pipeline with raw s_barrier (no vmcnt(0) drain in the main loop).
// ---------------------------------------------------------------------------
__global__ __launch_bounds__(512, 2) void argmin_kernel(
    const f16* __restrict__ xh, const f16* __restrict__ xl,
    const f16* __restrict__ eh, const f16* __restrict__ el,
    const float* __restrict__ e2, int* __restrict__ flat_ind)
{
    // buf b at b*32768: A [4 gran][256 row]x16B (16KB) then B same (16KB).
    // e2 stash at 98304 (2048 floats).
    __shared__ __align__(16) char lds[3 * 32768 + 8192];
    float* e2s = (float*)(lds + 98304);

    const int tid  = threadIdx.x;
    const int w    = tid >> 6;
    const int lane = tid & 63;
    const int l15  = lane & 15;
    const int l4   = lane >> 4;
    const int wrb  = (w >> 1) * 64;    // 4 row groups of 64
    const int wcb  = (w & 1) * 128;    // 2 col groups of 128
    const int row0 = blockIdx.x * BM;

    // staging coords (wave-uniform granule, per-lane row/col)
    const int rc = (w & 3) * 64 + lane;  // row (A) / col (B) 0..255
    const int g0 = w >> 2;               // granule 0/1; +2 for second load

    f32x4 acc[4][8];
    float best[16];
    int   bidx[16];
    #pragma unroll
    for (int t = 0; t < 16; ++t) { best[t] = 3.4e38f; bidx[t] = 0; }

    auto stage = [&](int skt, int sss, int buf) {
        const int prt = sss >> 3;             // 0: xh.eh  1: xh.el  2: xl.eh
        const int dt  = (sss & 7) * 32;
        const f16* as = (prt < 2) ? xh : xl;
        const f16* bs = (prt == 1) ? el : eh;
        char* base = &lds[buf * 32768];
        const f16* arow = as + (size_t)(row0 + rc) * DIM + dt;
        const f16* brow = bs + (size_t)(skt * 256 + rc) * DIM + dt;
        gload_lds16(arow + g0 * 8,       base + g0 * 4096 + rc * 16);
        gload_lds16(arow + (g0 + 2) * 8, base + (g0 + 2) * 4096 + rc * 16);
        gload_lds16(brow + g0 * 8,       base + 16384 + g0 * 4096 + rc * 16);
        gload_lds16(brow + (g0 + 2) * 8, base + 16384 + (g0 + 2) * 4096 + rc * 16);
    };

    auto compute = [&](int buf) {
        const char* base = &lds[buf * 32768];
        f16x8 a[4], b[8];
        #pragma unroll
        for (int i = 0; i < 4; ++i)
            a[i] = *(const f16x8*)(base + l4 * 4096 + (wrb + i * 16 + l15) * 16);
        #pragma unroll
        for (int j = 0; j < 8; ++j)
            b[j] = *(const f16x8*)(base + 16384 + l4 * 4096 + (wcb + j * 16 + l15) * 16);
        #pragma unroll
        for (int i = 0; i < 4; ++i)
            #pragma unroll
            for (int j = 0; j < 8; ++j)
                acc[i][j] = MFMA16(a[i], b[j], acc[i][j]);
    };

    // prologue: e2 stash + first two stages, then a full sync (drains once).
    ((f32x4*)e2s)[tid] = ((const f32x4*)e2)[tid];
    stage(0, 0, 0);
    stage(0, 1, 1);
    __syncthreads();

    int skt = 0, sss = 2;   // next stage virtual index
    int bs2 = 2;            // next stage buffer
    int bc  = 0;            // compute buffer

    for (int kt = 0; kt < NKT; ++kt) {
        #pragma unroll
        for (int i = 0; i < 4; ++i)
            #pragma unroll
            for (int j = 0; j < 8; ++j)
                acc[i][j] = (f32x4){0.f, 0.f, 0.f, 0.f};

        for (int ss = 0; ss < 24; ++ss) {
            const int s = kt * 24 + ss;
            if (s < STEPS - 1) asm volatile("s_waitcnt vmcnt(4)" ::: "memory");
            else               asm volatile("s_waitcnt vmcnt(0)" ::: "memory");
            __builtin_amdgcn_s_barrier();
            __builtin_amdgcn_sched_barrier(0);
            if (s < STEPS - 2) {
                stage(skt, sss, bs2);
                if (++sss == 24) { sss = 0; ++skt; }
                if (++bs2 == 3) bs2 = 0;
            }
            compute(bc);
            if (++bc == 3) bc = 0;
        }

        // epilogue: fold this 256-code tile into the running per-row argmin
        #pragma unroll
        for (int j = 0; j < 8; ++j) {
            const int col = kt * 256 + wcb + j * 16 + l15;
            const float e2v = e2s[col];
            #pragma unroll
            for (int i = 0; i < 4; ++i)
                #pragma unroll
                for (int r = 0; r < 4; ++r) {
                    float m = fmaf(-2.0f, acc[i][j][r], e2v);
                    const int t = i * 4 + r;
                    if (m < best[t]) { best[t] = m; bidx[t] = col; }
                }
        }
    }

    // final reduce: over the 16 col-lanes (l15), then over the 2 col-waves.
    __syncthreads();
    float* rv = (float*)lds;
    int*   ri = (int*)(lds + 2048);
    #pragma unroll
    for (int t = 0; t < 16; ++t) {
        float v = best[t];
        int  ix = bidx[t];
        #pragma unroll
        for (int m = 1; m <= 8; m <<= 1) {
            float ov = __shfl_xor(v, m, 64);
            int  oix = __shfl_xor(ix, m, 64);
            if (ov < v || (ov == v && oix < ix)) { v = ov; ix = oix; }
        }
        if (l15 == 0) {
            const int rl = wrb + (t >> 2) * 16 + l4 * 4 + (t & 3);
            rv[rl * 2 + (w & 1)] = v;
            ri[rl * 2 + (w & 1)] = ix;
        }
    }
    __syncthreads();
    if (tid < BM) {
        float v0 = rv[tid * 2], v1 = rv[tid * 2 + 1];
        int   i0 = ri[tid * 2], i1 = ri[tid * 2 + 1];
        flat_ind[row0 + tid] = (v1 < v0 || (v1 == v0 && i1 < i0)) ? i1 : i0;
    }
}

// ---------------------------------------------------------------------------
// scatter: quantize gather + EMA scatter-add + index output
// ---------------------------------------------------------------------------
__global__ __launch_bounds__(256) void scatter_kernel(
    const float* __restrict__ x, const float* __restrict__ embed,
    const int* __restrict__ flat_ind,
    float* __restrict__ out_q, float* __restrict__ out_ind_f,
    float* __restrict__ sums, float* __restrict__ counts)
{
    int row = blockIdx.x;
    int d   = threadIdx.x;
    int ind = flat_ind[row];
    float v = x[(size_t)row * DIM + d];
    out_q[(size_t)row * DIM + d] = embed[ind * DIM + d];
    atomicAdd(&sums[ind * DIM + d], v);
    if (d == 0) {
        out_ind_f[row] = (float)ind;
        atomicAdd(&counts[ind], 1.0f);
    }
}

// ---------------------------------------------------------------------------
// finalize: EMA update outputs
// ---------------------------------------------------------------------------
__global__ __launch_bounds__(256) void finalize_kernel(
    const float* __restrict__ embed_sum, const float* __restrict__ usage,
    const float* __restrict__ sums, const float* __restrict__ counts,
    float* __restrict__ out_usage, float* __restrict__ out_embed_sum)
{
    int k = blockIdx.x;
    int d = threadIdx.x;
    out_embed_sum[k * DIM + d] =
        embed_sum[k * DIM + d] * DECAYF + sums[k * DIM + d] * (1.0f - DECAYF);
    if (d == 0)
        out_usage[k] = usage[k] * DECAYF + counts[k] * (1.0f - DECAYF);
}

extern "C" void kernel_launch(void* const* d_in, const int* in_sizes, int n_in,
                              void* d_out, int out_size, void* d_ws, size_t ws_size,
                              hipStream_t stream)
{
    const float* hs        = (const float*)d_in[0];
    const float* embed_sum = (const float*)d_in[1];
    const float* usage     = (const float*)d_in[2];
    const int N = in_sizes[0] / DIM;   // 65536

    float* ws_f   = (float*)d_ws;
    float* embed  = ws_f;                         // K*D
    float* e2     = embed + KCODES * DIM;         // K
    float* sums   = e2 + KCODES;                  // K*D
    float* counts = sums + KCODES * DIM;          // K
    f16*   eh     = (f16*)(counts + KCODES);      // K*D f16
    f16*   el     = eh + KCODES * DIM;            // K*D f16
    int* flat_ind = (int*)(el + KCODES * DIM);    // N

    float* out_q     = (float*)d_out;             // N*D
    float* out_ind   = out_q + (size_t)N * DIM;   // N
    float* out_usage = out_ind + N;               // K
    float* out_es    = out_usage + KCODES;        // K*D

    // xh/xl live in the out_q region (64MB = N*D*4B exactly); scatter
    // overwrites out_q afterwards, so no conflict.
    f16* xh = (f16*)out_q;                        // N*D f16 (32MB)
    f16* xl = xh + (size_t)N * DIM;               // N*D f16 (32MB)

    hipMemsetAsync(sums, 0, (size_t)(KCODES * DIM + KCODES) * sizeof(float), stream);

    split_x_kernel<<<(N * DIM / 8 + 255) / 256, 256, 0, stream>>>(hs, xh, xl, N * DIM / 8);
    prep_embed_kernel<<<KCODES, 256, 0, stream>>>(embed_sum, usage, embed, eh, el, e2);
    argmin_kernel<<<N / BM, 512, 0, stream>>>(xh, xl, eh, el, e2, flat_ind);
    scatter_kernel<<<N, 256, 0, stream>>>(hs, embed, flat_ind, out_q, out_ind, sums, counts);
    finalize_kernel<<<KCODES, 256, 0, stream>>>(embed_sum, usage, sums, counts, out_usage, out_es);
}